// Round 13
// baseline (40219.073 us; speedup 1.0000x reference)
//
#include <hip/hip_runtime.h>
#include <hip/hip_bf16.h>

#define SEQ 1024
#define HID 2048
#define BAT 128
#define VOC 256
#define BN 96              // cols per block (halves coherent A redundancy)
#define NG 24              // col groups
#define MG 4               // row groups (128/32)
#define RING 3             // h ring slots (barrier-ordered)
#define RSTR 52            // reduce LDS row stride (dwords)
#define RWAVE 1664         // 32*52 dwords per wave slot

typedef __attribute__((ext_vector_type(4))) unsigned u32x4;
typedef __attribute__((ext_vector_type(8))) short short8;
typedef __attribute__((ext_vector_type(4))) float f32x4;

// counted vmem wait + scheduler fence (rule #18)
#define WAITVM(N) do { asm volatile("s_waitcnt vmcnt(" #N ")" ::: "memory"); \
                       __builtin_amdgcn_sched_barrier(0); } while (0)
// block barrier with LDS drain + compiler memory fence
#define BARRIER() asm volatile("s_waitcnt lgkmcnt(0)\n\ts_barrier" ::: "memory")

// --- asm memory ops (data-only paths; never address-forming) ----------------
__device__ __forceinline__ u32x4 ld16(const void* p) {          // cached L1/L2
    u32x4 r; asm volatile("global_load_dwordx4 %0, %1, off" : "=v"(r) : "v"(p)); return r;
}
__device__ __forceinline__ u32x4 ld16_coh(const void* p) {      // bypass -> LLC
    u32x4 r; asm volatile("global_load_dwordx4 %0, %1, off sc0 sc1" : "=v"(r) : "v"(p)); return r;
}
__device__ __forceinline__ unsigned ld4_poll(const void* p) {   // fresh LLC read
    unsigned r;
    asm volatile("global_load_dword %0, %1, off sc0 sc1\n\ts_waitcnt vmcnt(0)"
                 : "=v"(r) : "v"(p) : "memory");
    return r;
}
// h-store: 8B atomic swap (no return) -> completes AT the LLC coherence point
__device__ __forceinline__ void swap8(void* p, unsigned long long v) {
    asm volatile("global_atomic_swap_x2 %0, %1, off" :: "v"(p), "v"(v) : "memory");
}
__device__ __forceinline__ void st16_nt(void* p, f32x4 v) {
    asm volatile("global_store_dwordx4 %0, %1, off nt" :: "v"(p), "v"(v) : "memory");
}

// --- bf16 helpers -----------------------------------------------------------
__device__ __forceinline__ unsigned short f2bf_rn(float v) {
    unsigned u = __float_as_uint(v);
    u += 0x7fffu + ((u >> 16) & 1u);
    return (unsigned short)(u >> 16);
}
__device__ __forceinline__ float bf2f(unsigned short s) {
    return __uint_as_float(((unsigned)s) << 16);
}

// ---------------------------------------------------------------------------
// prologue: Wg[ng][192][2048] bf16 — rows 0..95 hi, 96..191 lo of 96 cols.
// ---------------------------------------------------------------------------
__global__ __launch_bounds__(256) void wsplit(
    const float* __restrict__ Whh, const float* __restrict__ Wlin,
    short* __restrict__ Wg)
{
    const int n  = blockIdx.x;          // 0..2303
    const int ng = n / BN, rl = n % BN;
    short* dhi = Wg + ((size_t)ng * 192 + rl) * HID;
    short* dlo = dhi + (size_t)BN * HID;
    for (int k = threadIdx.x; k < HID; k += 256) {
        float v = (n < HID) ? Whh[(size_t)k * HID + n]
                            : Wlin[(size_t)k * VOC + (n - HID)];
        unsigned short h = f2bf_rn(v);
        dhi[k] = (short)h;
        dlo[k] = (short)f2bf_rn(v - bf2f(h));
    }
}

// ---------------------------------------------------------------------------
// init: h0 -> plain bf16, ring slot 0; zero barrier counters.
// ---------------------------------------------------------------------------
__global__ __launch_bounds__(256) void hsplit(
    const float* __restrict__ h0, unsigned short* __restrict__ hb,
    unsigned* __restrict__ cnt)
{
    if (blockIdx.x == 0 && threadIdx.x < MG)
        __hip_atomic_store(&cnt[threadIdx.x * 32], 0u, __ATOMIC_RELAXED,
                           __HIP_MEMORY_SCOPE_SYSTEM);
    for (int i = blockIdx.x * 256 + threadIdx.x; i < BAT * HID;
         i += gridDim.x * 256) {
        hb[i] = f2bf_rn(h0[i]);
    }
}

// ---------------------------------------------------------------------------
// persistent kernel: BN=96 geometry — 96 blocks, each wave owns a K-256
// slice and ALL 96 block-columns. Coherent A traffic halves vs BN=48.
// ---------------------------------------------------------------------------
__global__ __launch_bounds__(512, 1) void rnn_all(
    unsigned short* __restrict__ hb, const short* __restrict__ Wg,
    const float* __restrict__ Wxh, const float* __restrict__ bh,
    const float* __restrict__ blin, const int* __restrict__ x,
    float* __restrict__ out, unsigned* __restrict__ cnt)
{
    __shared__ __align__(16) float red[8][RWAVE];

    const int tid  = threadIdx.x;
    const int wv   = tid >> 6, lane = tid & 63;
    const int l15  = lane & 15, lq = lane >> 4;
    const int ng   = blockIdx.x;           // 0..23 (ng%8 -> XCD spread)
    const int mg   = blockIdx.y;           // 0..3  (independent sync domain)
    const int ks   = wv;                   // K-slice owner: [ks*256, ks*256+256)
    const short* Wgb = Wg + (size_t)ng * 192 * HID;
    const bool  has_y = (ng * BN + BN > HID);   // ng >= 21

    // epilogue ownership: threads 0..383 own (row, 4 cols) x 2 passes
    const bool ep   = (tid < 384);
    const int  erow = ep ? (tid / 12) : 0;
    const int  ecol = ep ? ((tid % 12) * 4) : 0;
    const int  grow = mg * 32 + erow;
    const int  gc0  = ng * BN + ecol;          // pass-0 column
    const int  gc1  = gc0 + 48;                // pass-1 column
    const bool eh0  = ep && (gc0 < HID);
    const bool eh1  = ep && (gc1 < HID);
    const bool ey0  = ep && (gc0 >= HID);
    const bool ey1  = ep && (gc1 >= HID);

    f32x4 add4[2] = {{0,0,0,0},{0,0,0,0}};
    f32x4 wx4[2]  = {{0,0,0,0},{0,0,0,0}};
    if (ep) {
        add4[0] = eh0 ? *(const f32x4*)&bh[gc0] : *(const f32x4*)&blin[gc0 - HID];
        add4[1] = eh1 ? *(const f32x4*)&bh[gc1] : *(const f32x4*)&blin[gc1 - HID];
        if (eh0) {
            int xv0 = x[(size_t)grow * SEQ];
            wx4[0] = *(const f32x4*)&Wxh[(size_t)xv0 * HID + gc0];
            if (eh1) wx4[1] = *(const f32x4*)&Wxh[(size_t)xv0 * HID + gc1];
        }
    }

    u32x4 aA[3][2];      // [slot][mi]       A: bf16 h, coherent, 3-deep
    u32x4 bB[2][6][2];   // [slot][ni][hi/lo] B: bf16 planes, cached, 2-deep

    auto issueB = [&](int k, int buf) {          // 12 loads
        const int kb = ks * 256 + k * 32;
        #pragma unroll
        for (int ni = 0; ni < 6; ++ni) {
            const short* p = Wgb + (size_t)(ni * 16 + l15) * HID + kb + lq * 8;
            bB[buf][ni][0] = ld16(p);
            bB[buf][ni][1] = ld16(p + (size_t)BN * HID);
        }
    };
    auto issueA = [&](const unsigned short* Hp, int k, int slot) {  // 2 loads
        const int kb = ks * 256 + k * 32;
        #pragma unroll
        for (int mi = 0; mi < 2; ++mi) {
            const unsigned short* p =
                Hp + (size_t)(mg * 32 + mi * 16 + l15) * HID + kb + lq * 8;
            aA[slot][mi] = ld16_coh(p);
        }
    };

    // prologue prefetch: B batches 0,1 (24 ops)
    issueB(0, 0); issueB(1, 1);

    #pragma unroll 1
    for (int t = 0; ; ++t) {
        const bool last = (t == SEQ);
        if (last && !has_y) break;
        const unsigned short* Hp = hb + (size_t)(t % RING) * BAT * HID;
        unsigned short*       Hn = hb + (size_t)((t + 1) % RING) * BAT * HID;

        issueA(Hp, 0, 0); issueA(Hp, 1, 1); issueA(Hp, 2, 2);   // 6 ops

        f32x4 acc[2][6];
        #pragma unroll
        for (int mi = 0; mi < 2; ++mi)
            #pragma unroll
            for (int ni = 0; ni < 6; ++ni)
                acc[mi][ni] = (f32x4){0.f, 0.f, 0.f, 0.f};

        // ---- K-loop: 8 batches (12B+2A), B 2-deep / A 3-deep, issue-after-use
        // waits derived for issue order [B0 B1 | A0 A1 A2 | B2 A3 | B3 A4 |...]
        #pragma unroll
        for (int k = 0; k < 8; ++k) {
            if (k == 0)      WAITVM(4);
            else if (k == 6) WAITVM(14);
            else if (k == 7) WAITVM(0);
            else             WAITVM(16);
            #pragma unroll
            for (int mi = 0; mi < 2; ++mi) {
                short8 ah = __builtin_bit_cast(short8, aA[k % 3][mi]);
                #pragma unroll
                for (int ni = 0; ni < 6; ++ni) {
                    short8 bhv = __builtin_bit_cast(short8, bB[k & 1][ni][0]);
                    short8 blv = __builtin_bit_cast(short8, bB[k & 1][ni][1]);
                    acc[mi][ni] = __builtin_amdgcn_mfma_f32_16x16x32_bf16(ah, bhv, acc[mi][ni], 0, 0, 0);
                    acc[mi][ni] = __builtin_amdgcn_mfma_f32_16x16x32_bf16(ah, blv, acc[mi][ni], 0, 0, 0);
                }
            }
            if (k < 6) issueB(k + 2, k & 1);
            if (k < 5) issueA(Hp, k + 3, k % 3);
        }

        // next-step x/Wxh gather — plain loads (compiler-managed waits)
        f32x4 wxn[2] = {{0,0,0,0},{0,0,0,0}};
        if (eh0 && !last) {
            const int tn = (t + 1 < SEQ) ? (t + 1) : (SEQ - 1);
            int xvn = x[(size_t)grow * SEQ + tn];
            wxn[0] = *(const f32x4*)&Wxh[(size_t)xvn * HID + gc0];
            if (eh1) wxn[1] = *(const f32x4*)&Wxh[(size_t)xvn * HID + gc1];
        }

        // ---- cross-wave reduce: two 48-col passes over one 53 KB buffer ----
        f32x4 sum[2];
        #pragma unroll
        for (int p = 0; p < 2; ++p) {
            if (p) BARRIER();                   // reads of pass0 done
            #pragma unroll
            for (int mi = 0; mi < 2; ++mi)
                #pragma unroll
                for (int nj = 0; nj < 3; ++nj)
                    #pragma unroll
                    for (int r = 0; r < 4; ++r)
                        red[wv][(mi * 16 + lq * 4 + r) * RSTR + nj * 16 + l15] =
                            acc[mi][p * 3 + nj][r];
            BARRIER();
            sum[p] = (f32x4){0.f, 0.f, 0.f, 0.f};
            if (ep) {
                #pragma unroll
                for (int w = 0; w < 8; ++w)
                    sum[p] += *(const f32x4*)&red[w][erow * RSTR + ecol];
            }
        }

        // ---- epilogue (both passes) ---------------------------------------
        #pragma unroll
        for (int p = 0; p < 2; ++p) {
            const bool ehp = p ? eh1 : eh0;
            const bool eyp = p ? ey1 : ey0;
            const int  gcp = p ? gc1 : gc0;
            if (ehp && !last) {
                float th0 = tanhf(sum[p][0] + wx4[p][0] + add4[p][0]);
                float th1 = tanhf(sum[p][1] + wx4[p][1] + add4[p][1]);
                float th2 = tanhf(sum[p][2] + wx4[p][2] + add4[p][2]);
                float th3 = tanhf(sum[p][3] + wx4[p][3] + add4[p][3]);
                unsigned long long q =
                      (unsigned long long)f2bf_rn(th0)
                    | ((unsigned long long)f2bf_rn(th1) << 16)
                    | ((unsigned long long)f2bf_rn(th2) << 32)
                    | ((unsigned long long)f2bf_rn(th3) << 48);
                swap8(Hn + (size_t)grow * HID + gcp, q);
                if (t == SEQ - 1) {
                    f32x4 hv = {th0, th1, th2, th3};
                    st16_nt(&out[(size_t)BAT * SEQ * VOC + (size_t)grow * HID + gcp], hv);
                }
            } else if (eyp && t > 0) {
                st16_nt(&out[((size_t)grow * SEQ + (t - 1)) * VOC + (gcp - HID)],
                        sum[p] + add4[p]);
            }
        }

        if (last) break;
        wx4[0] = wxn[0]; wx4[1] = wxn[1];

        // next-step B prefetch rides across the barrier (W immutable)
        issueB(0, 0); issueB(1, 1);
        WAITVM(24);                             // drains h/y stores; keeps 24 B
        BARRIER();

        // ---- mg-local grid barrier (24 blocks, private cache line) ---------
        if (tid == 0) {
            unsigned* c = &cnt[mg * 32];
            __hip_atomic_fetch_add(c, 1u, __ATOMIC_RELAXED, __HIP_MEMORY_SCOPE_AGENT);
            const unsigned target = 24u * (unsigned)(t + 1);
            int spins = 0;
            while (ld4_poll(c) < target) {
                __builtin_amdgcn_s_sleep(1);
                if (++spins > (1 << 22)) break;  // safety valve
            }
        }
        BARRIER();
    }
    WAITVM(0);
}

// ---------------------------------------------------------------------------
extern "C" void kernel_launch(void* const* d_in, const int* in_sizes, int n_in,
                              void* d_out, int out_size, void* d_ws, size_t ws_size,
                              hipStream_t stream) {
    const int*   x    = (const int*)  d_in[0];
    const float* h0   = (const float*)d_in[1];
    const float* Wxh  = (const float*)d_in[2];
    const float* Whh  = (const float*)d_in[3];
    const float* bh   = (const float*)d_in[4];
    const float* Wlin = (const float*)d_in[5];
    const float* blin = (const float*)d_in[6];
    float* out = (float*)d_out;

    // ws: Wg shorts [24*192*2048] | hb bf16 [RING*128*2048] | cnt u32 [128]
    short*          Wg  = (short*)d_ws;
    unsigned short* hb  = (unsigned short*)(Wg + (size_t)NG * 192 * HID);
    unsigned*       cnt = (unsigned*)(hb + (size_t)RING * BAT * HID);

    wsplit<<<dim3(HID + VOC), 256, 0, stream>>>(Whh, Wlin, Wg);
    hsplit<<<dim3(256), 256, 0, stream>>>(h0, hb, cnt);
    rnn_all<<<dim3(NG, MG), 512, 0, stream>>>(hb, Wg, Wxh, bh, blin, x, out, cnt);
}

// Round 14
// 33106.470 us; speedup vs baseline: 1.2148x; 1.2148x over previous
//
#include <hip/hip_runtime.h>
#include <hip/hip_bf16.h>

#define SEQ 1024
#define HID 2048
#define BAT 128
#define VOC 256
#define BN 96              // cols per block
#define NG 24              // col groups  (coherent A bytes = NG * 0.5 MB)
#define MG 8               // row groups  (grid = NG*MG = 192 blocks)
#define BM 16              // rows per block (128/MG)
#define RING 3             // h ring slots (barrier-ordered)
#define RSTR 100           // reduce LDS row stride (dwords, 96+4)

typedef __attribute__((ext_vector_type(4))) unsigned u32x4;
typedef __attribute__((ext_vector_type(8))) short short8;
typedef __attribute__((ext_vector_type(4))) float f32x4;

// counted vmem wait + scheduler fence (rule #18)
#define WAITVM(N) do { asm volatile("s_waitcnt vmcnt(" #N ")" ::: "memory"); \
                       __builtin_amdgcn_sched_barrier(0); } while (0)
// block barrier with LDS drain + compiler memory fence
#define BARRIER() asm volatile("s_waitcnt lgkmcnt(0)\n\ts_barrier" ::: "memory")

// --- asm memory ops (data-only paths; never address-forming) ----------------
__device__ __forceinline__ u32x4 ld16(const void* p) {          // cached L1/L2
    u32x4 r; asm volatile("global_load_dwordx4 %0, %1, off" : "=v"(r) : "v"(p)); return r;
}
__device__ __forceinline__ u32x4 ld16_coh(const void* p) {      // bypass -> LLC
    u32x4 r; asm volatile("global_load_dwordx4 %0, %1, off sc0 sc1" : "=v"(r) : "v"(p)); return r;
}
__device__ __forceinline__ unsigned ld4_poll(const void* p) {   // fresh LLC read
    unsigned r;
    asm volatile("global_load_dword %0, %1, off sc0 sc1\n\ts_waitcnt vmcnt(0)"
                 : "=v"(r) : "v"(p) : "memory");
    return r;
}
// h-store: 8B atomic swap (no return) -> completes AT the LLC coherence point
__device__ __forceinline__ void swap8(void* p, unsigned long long v) {
    asm volatile("global_atomic_swap_x2 %0, %1, off" :: "v"(p), "v"(v) : "memory");
}
__device__ __forceinline__ void st16_nt(void* p, f32x4 v) {
    asm volatile("global_store_dwordx4 %0, %1, off nt" :: "v"(p), "v"(v) : "memory");
}

// --- bf16 helpers -----------------------------------------------------------
__device__ __forceinline__ unsigned short f2bf_rn(float v) {
    unsigned u = __float_as_uint(v);
    u += 0x7fffu + ((u >> 16) & 1u);
    return (unsigned short)(u >> 16);
}
__device__ __forceinline__ float bf2f(unsigned short s) {
    return __uint_as_float(((unsigned)s) << 16);
}

// ---------------------------------------------------------------------------
// prologue: Wg[ng][192][2048] bf16 — rows 0..95 hi, 96..191 lo of 96 cols.
// ---------------------------------------------------------------------------
__global__ __launch_bounds__(256) void wsplit(
    const float* __restrict__ Whh, const float* __restrict__ Wlin,
    short* __restrict__ Wg)
{
    const int n  = blockIdx.x;          // 0..2303
    const int ng = n / BN, rl = n % BN;
    short* dhi = Wg + ((size_t)ng * 192 + rl) * HID;
    short* dlo = dhi + (size_t)BN * HID;
    for (int k = threadIdx.x; k < HID; k += 256) {
        float v = (n < HID) ? Whh[(size_t)k * HID + n]
                            : Wlin[(size_t)k * VOC + (n - HID)];
        unsigned short h = f2bf_rn(v);
        dhi[k] = (short)h;
        dlo[k] = (short)f2bf_rn(v - bf2f(h));
    }
}

// ---------------------------------------------------------------------------
// init: h0 -> plain bf16, ring slot 0; zero barrier counters.
// ---------------------------------------------------------------------------
__global__ __launch_bounds__(256) void hsplit(
    const float* __restrict__ h0, unsigned short* __restrict__ hb,
    unsigned* __restrict__ cnt)
{
    if (blockIdx.x == 0 && threadIdx.x < MG)
        __hip_atomic_store(&cnt[threadIdx.x * 32], 0u, __ATOMIC_RELAXED,
                           __HIP_MEMORY_SCOPE_SYSTEM);
    for (int i = blockIdx.x * 256 + threadIdx.x; i < BAT * HID;
         i += gridDim.x * 256) {
        hb[i] = f2bf_rn(h0[i]);
    }
}

// ---------------------------------------------------------------------------
// persistent kernel: 192 blocks = 24 col-groups x 8 row-groups of 16 rows.
// Coherent A traffic = 12.3 MB/step (half of r10) at unchanged parallelism;
// B-stream 786 KB/block overlaps it via the counted-vmcnt pipeline.
// ---------------------------------------------------------------------------
__global__ __launch_bounds__(512, 1) void rnn_all(
    unsigned short* __restrict__ hb, const short* __restrict__ Wg,
    const float* __restrict__ Wxh, const float* __restrict__ bh,
    const float* __restrict__ blin, const int* __restrict__ x,
    float* __restrict__ out, unsigned* __restrict__ cnt)
{
    __shared__ __align__(16) float red[8][BM * RSTR];

    const int tid  = threadIdx.x;
    const int wv   = tid >> 6, lane = tid & 63;
    const int l15  = lane & 15, lq = lane >> 4;
    const int ng   = blockIdx.x;           // 0..23 (ng%8 -> XCD spread)
    const int mg   = blockIdx.y;           // 0..7  (independent sync domain)
    const int ks   = wv;                   // K-slice owner: [ks*256, ks*256+256)
    const short* Wgb = Wg + (size_t)ng * 192 * HID;
    const bool  has_y = (ng * BN + BN > HID);   // ng >= 21

    // epilogue ownership: threads 0..383 own (row, 4 consecutive cols)
    const bool ep   = (tid < 384);
    const int  erow = ep ? (tid / 24) : 0;      // 0..15
    const int  ecol = ep ? ((tid % 24) * 4) : 0; // 0..92
    const int  grow = mg * BM + erow;
    const int  gcol = ng * BN + ecol;
    const bool ey   = ep && (gcol >= HID);
    const bool eh   = ep && (gcol <  HID);

    f32x4 add4 = {0.f, 0.f, 0.f, 0.f};
    f32x4 wx4  = {0.f, 0.f, 0.f, 0.f};
    if (eh) {
        add4 = *(const f32x4*)&bh[gcol];
        int xv0 = x[(size_t)grow * SEQ];
        wx4 = *(const f32x4*)&Wxh[(size_t)xv0 * HID + gcol];
    } else if (ey) {
        add4 = *(const f32x4*)&blin[gcol - HID];
    }

    u32x4 aA[3];         // [slot]            A: bf16 h rows, coherent, 3-deep
    u32x4 bB[2][6][2];   // [slot][ni][hi/lo] B: bf16 planes, cached, 2-deep

    auto issueB = [&](int k, int buf) {          // 12 loads
        const int kb = ks * 256 + k * 32;
        #pragma unroll
        for (int ni = 0; ni < 6; ++ni) {
            const short* p = Wgb + (size_t)(ni * 16 + l15) * HID + kb + lq * 8;
            bB[buf][ni][0] = ld16(p);
            bB[buf][ni][1] = ld16(p + (size_t)BN * HID);
        }
    };
    auto issueA = [&](const unsigned short* Hp, int k, int slot) {  // 1 load
        const int kb = ks * 256 + k * 32;
        const unsigned short* p =
            Hp + (size_t)(mg * BM + l15) * HID + kb + lq * 8;
        aA[slot] = ld16_coh(p);
    };

    // prologue prefetch: B batches 0,1 (24 ops)
    issueB(0, 0); issueB(1, 1);

    #pragma unroll 1
    for (int t = 0; ; ++t) {
        const bool last = (t == SEQ);
        if (last && !has_y) break;
        const unsigned short* Hp = hb + (size_t)(t % RING) * BAT * HID;
        unsigned short*       Hn = hb + (size_t)((t + 1) % RING) * BAT * HID;

        issueA(Hp, 0, 0); issueA(Hp, 1, 1); issueA(Hp, 2, 2);   // 3 ops

        f32x4 acc[6];
        #pragma unroll
        for (int ni = 0; ni < 6; ++ni) acc[ni] = (f32x4){0.f, 0.f, 0.f, 0.f};

        // ---- K-loop: 8 batches (12B + 1A), B 2-deep / A 3-deep -------------
        // issue order: [B0 B1 | A0 A1 A2 | B2 A3 | B3 A4 | ... | B7]
        // waits: k0=2, k1..5=14, k6=13, k7=0 (derivation in journal)
        #pragma unroll
        for (int k = 0; k < 8; ++k) {
            if (k == 0)      WAITVM(2);
            else if (k == 6) WAITVM(13);
            else if (k == 7) WAITVM(0);
            else             WAITVM(14);
            short8 ah = __builtin_bit_cast(short8, aA[k % 3]);
            #pragma unroll
            for (int ni = 0; ni < 6; ++ni) {
                short8 bhv = __builtin_bit_cast(short8, bB[k & 1][ni][0]);
                short8 blv = __builtin_bit_cast(short8, bB[k & 1][ni][1]);
                acc[ni] = __builtin_amdgcn_mfma_f32_16x16x32_bf16(ah, bhv, acc[ni], 0, 0, 0);
                acc[ni] = __builtin_amdgcn_mfma_f32_16x16x32_bf16(ah, blv, acc[ni], 0, 0, 0);
            }
            if (k < 6) issueB(k + 2, k & 1);
            if (k < 5) issueA(Hp, k + 3, k % 3);
        }

        // next-step x/Wxh gather — plain loads (compiler-managed waits)
        f32x4 wxn = {0.f, 0.f, 0.f, 0.f};
        if (eh && !last) {
            const int tn = (t + 1 < SEQ) ? (t + 1) : (SEQ - 1);
            int xvn = x[(size_t)grow * SEQ + tn];
            wxn = *(const f32x4*)&Wxh[(size_t)xvn * HID + gcol];
        }

        // ---- cross-wave reduce (one block barrier) -------------------------
        #pragma unroll
        for (int ni = 0; ni < 6; ++ni)
            #pragma unroll
            for (int r = 0; r < 4; ++r)
                red[wv][(lq * 4 + r) * RSTR + ni * 16 + l15] = acc[ni][r];
        BARRIER();
        f32x4 sum = {0.f, 0.f, 0.f, 0.f};
        if (ep) {
            #pragma unroll
            for (int w = 0; w < 8; ++w)
                sum += *(const f32x4*)&red[w][erow * RSTR + ecol];
        }

        // ---- epilogue ------------------------------------------------------
        if (eh && !last) {
            float th0 = tanhf(sum[0] + wx4[0] + add4[0]);
            float th1 = tanhf(sum[1] + wx4[1] + add4[1]);
            float th2 = tanhf(sum[2] + wx4[2] + add4[2]);
            float th3 = tanhf(sum[3] + wx4[3] + add4[3]);
            unsigned long long q =
                  (unsigned long long)f2bf_rn(th0)
                | ((unsigned long long)f2bf_rn(th1) << 16)
                | ((unsigned long long)f2bf_rn(th2) << 32)
                | ((unsigned long long)f2bf_rn(th3) << 48);
            swap8(Hn + (size_t)grow * HID + gcol, q);
            if (t == SEQ - 1) {
                f32x4 hv = {th0, th1, th2, th3};
                st16_nt(&out[(size_t)BAT * SEQ * VOC + (size_t)grow * HID + gcol], hv);
            }
        } else if (ey && t > 0) {
            st16_nt(&out[((size_t)grow * SEQ + (t - 1)) * VOC + (gcol - HID)], sum + add4);
        }

        if (last) break;
        wx4 = wxn;

        // next-step B prefetch rides across the barrier (W immutable)
        issueB(0, 0); issueB(1, 1);
        WAITVM(24);                             // drains h/y stores; keeps 24 B
        BARRIER();

        // ---- mg-local grid barrier (24 blocks, private cache line) ---------
        if (tid == 0) {
            unsigned* c = &cnt[mg * 32];
            __hip_atomic_fetch_add(c, 1u, __ATOMIC_RELAXED, __HIP_MEMORY_SCOPE_AGENT);
            const unsigned target = 24u * (unsigned)(t + 1);
            int spins = 0;
            while (ld4_poll(c) < target) {
                __builtin_amdgcn_s_sleep(1);
                if (++spins > (1 << 22)) break;  // safety valve
            }
        }
        BARRIER();
    }
    WAITVM(0);
}

// ---------------------------------------------------------------------------
extern "C" void kernel_launch(void* const* d_in, const int* in_sizes, int n_in,
                              void* d_out, int out_size, void* d_ws, size_t ws_size,
                              hipStream_t stream) {
    const int*   x    = (const int*)  d_in[0];
    const float* h0   = (const float*)d_in[1];
    const float* Wxh  = (const float*)d_in[2];
    const float* Whh  = (const float*)d_in[3];
    const float* bh   = (const float*)d_in[4];
    const float* Wlin = (const float*)d_in[5];
    const float* blin = (const float*)d_in[6];
    float* out = (float*)d_out;

    // ws: Wg shorts [24*192*2048] | hb bf16 [RING*128*2048] | cnt u32 [256]
    short*          Wg  = (short*)d_ws;
    unsigned short* hb  = (unsigned short*)(Wg + (size_t)NG * 192 * HID);
    unsigned*       cnt = (unsigned*)(hb + (size_t)RING * BAT * HID);

    wsplit<<<dim3(HID + VOC), 256, 0, stream>>>(Whh, Wlin, Wg);
    hsplit<<<dim3(256), 256, 0, stream>>>(h0, hb, cnt);
    rnn_all<<<dim3(NG, MG), 512, 0, stream>>>(hb, Wg, Wxh, bh, blin, x, out, cnt);
}